// Round 8
// baseline (166.778 us; speedup 1.0000x reference)
//
#include <hip/hip_runtime.h>
#include <math.h>

#define N 8192
#define D 64
#define KK 5                  // K-steps of 16 (K=80: 64 data + 4 norm + 12 zero)
#define REP 8                 // DIAGNOSTIC: repeat sweep; state reset per rep => result identical
#define JSPLIT 32
#define JTPW (256 / JSPLIT)   // 8 jtiles per wave
#define LOG2E 1.4426950408889634f
#define C2 2.0813689810056077f
#define SA (-2.0f * LOG2E)
#define SB LOG2E
#define LN2 0.6931471805599453f
#define BIG 3.0e38f
#define EXPBIAS 0.9608944f
#define EXPMAGIC 1065353216.0f
#define EXPSCALE -8388608.0f

typedef short bf16x8 __attribute__((ext_vector_type(8)));
typedef float f32x16 __attribute__((ext_vector_type(16)));

static __device__ __forceinline__ unsigned short f2bf(float f) {
    unsigned int u = __float_as_uint(f);
    return (unsigned short)((u + 0x7fffu + ((u >> 16) & 1u)) >> 16);
}

// Fragment layout (validated r2-r7): 16B slot s = (tile*KK + kk)*64 + lane;
// lane l holds row (l&31), k = kk*16 + 8*(l>>5) + 0..7.
// A (xba): k<64 -> -2*log2e*x ; k=64..67 -> [nhi, nlo, 1, 1] ; rest 0
// B (xbb): k<64 ->    log2e*x ; k=64..67 -> [1, 1, nhi, nlo] ; rest 0
// => acc[j,i] = |log2e*(x_i - x_j)|^2  (norms folded into MFMA, r4-r7 validated)
__global__ __launch_bounds__(256) void prep_kernel(const float* __restrict__ x,
                                                   unsigned short* __restrict__ xba,
                                                   unsigned short* __restrict__ xbb) {
    const int u = blockIdx.x * 256 + threadIdx.x;
    const int r = u >> 3, oct = u & 7;
    const float4 v0 = *(const float4*)(x + r * D + oct * 8);
    const float4 v1 = *(const float4*)(x + r * D + oct * 8 + 4);
    float s = v0.x * v0.x + v0.y * v0.y + v0.z * v0.z + v0.w * v0.w
            + v1.x * v1.x + v1.y * v1.y + v1.z * v1.z + v1.w * v1.w;
    s += __shfl_xor(s, 1); s += __shfl_xor(s, 2); s += __shfl_xor(s, 4);

    const int slot = ((r >> 5) * KK + (oct >> 1)) * 64 + (r & 31) + 32 * (oct & 1);
    uint4 wa, wb;
    wa.x = (unsigned)f2bf(SA * v0.x) | ((unsigned)f2bf(SA * v0.y) << 16);
    wa.y = (unsigned)f2bf(SA * v0.z) | ((unsigned)f2bf(SA * v0.w) << 16);
    wa.z = (unsigned)f2bf(SA * v1.x) | ((unsigned)f2bf(SA * v1.y) << 16);
    wa.w = (unsigned)f2bf(SA * v1.z) | ((unsigned)f2bf(SA * v1.w) << 16);
    wb.x = (unsigned)f2bf(SB * v0.x) | ((unsigned)f2bf(SB * v0.y) << 16);
    wb.y = (unsigned)f2bf(SB * v0.z) | ((unsigned)f2bf(SB * v0.w) << 16);
    wb.z = (unsigned)f2bf(SB * v1.x) | ((unsigned)f2bf(SB * v1.y) << 16);
    wb.w = (unsigned)f2bf(SB * v1.z) | ((unsigned)f2bf(SB * v1.w) << 16);
    *(uint4*)(xba + (size_t)slot * 8) = wa;
    *(uint4*)(xbb + (size_t)slot * 8) = wb;

    const float np = C2 * s;
    const unsigned short nhi = f2bf(np);
    const unsigned short nlo = f2bf(np - __uint_as_float((unsigned)nhi << 16));
    const int nbase = ((r >> 5) * KK + 4) * 64 + (r & 31);
    const unsigned ONE2 = 0x3f803f80u;
    if (oct == 0) {
        uint4 w; w.x = (unsigned)nhi | ((unsigned)nlo << 16); w.y = ONE2; w.z = 0; w.w = 0;
        *(uint4*)(xba + (size_t)nbase * 8) = w;
    } else if (oct == 1) {
        uint4 w; w.x = 0; w.y = 0; w.z = 0; w.w = 0;
        *(uint4*)(xba + (size_t)(nbase + 32) * 8) = w;
    } else if (oct == 2) {
        uint4 w; w.x = ONE2; w.y = (unsigned)nhi | ((unsigned)nlo << 16); w.z = 0; w.w = 0;
        *(uint4*)(xbb + (size_t)nbase * 8) = w;
    } else if (oct == 3) {
        uint4 w; w.x = 0; w.y = 0; w.z = 0; w.w = 0;
        *(uint4*)(xbb + (size_t)(nbase + 32) * 8) = w;
    }
}

template<bool DIAG>
static __device__ __forceinline__ void epi(const f32x16& acc, int hi, int il,
                                           float& s1a, float& s2a, float& sea,
                                           float& s1b, float& s2b, float& seb) {
#pragma unroll
    for (int q = 0; q < 16; ++q) {
        float sq = acc[q];
        if (DIAG) {
            sq = fmaxf(sq, 0.0f);
            const bool self = ((q & 3) + 8 * (q >> 2) + 4 * hi) == il;
            sq = self ? BIG : sq;      // self: bit-exp saturates to -0.0, harmless
        }
        const float dd = __builtin_amdgcn_sqrtf(sq);       // log2e * dist
        const float ef = fmaf(dd, EXPSCALE, EXPMAGIC);     // fast 2^(-dd)
        const float e  = __int_as_float((int)ef);
        if (q & 1) { seb += e; s2b = __builtin_amdgcn_fmed3f(s1b, s2b, sq); s1b = fminf(s1b, sq); }
        else       { sea += e; s2a = __builtin_amdgcn_fmed3f(s1a, s2a, sq); s1a = fminf(s1a, sq); }
    }
}

__global__ __launch_bounds__(256, 4) void knn_mfma_kernel(
        const unsigned short* __restrict__ xba,
        const unsigned short* __restrict__ xbb,
        float* __restrict__ partials) {
    const int t = threadIdx.x;
    const int lane = t & 63;
    const int w = t >> 6;
    const int igg = blockIdx.x >> 5;          // 0..31
    const int js  = blockIdx.x & (JSPLIT - 1);
    const int ig  = igg * 4 + w;              // 0..127 : this wave's 64 i-rows
    const int it0 = ig * 2, it1 = it0 + 1;    // its two itiles
    const int il = lane & 31, hi = lane >> 5;

    bf16x8 xi0[KK], xi1[KK];
#pragma unroll
    for (int kk = 0; kk < KK; ++kk) {
        xi0[kk] = *(const bf16x8*)(xbb + ((size_t)(it0 * KK + kk) * 64 + lane) * 8);
        xi1[kk] = *(const bf16x8*)(xbb + ((size_t)(it1 * KK + kk) * 64 + lane) * 8);
    }

    float s1aA, s2aA, seaA, s1bA, s2bA, sebA;   // state for it0 (even/odd split)
    float s1aB, s2aB, seaB, s1bB, s2bB, sebB;   // state for it1
    const f32x16 zacc = {};

#pragma unroll 1
    for (int rep = 0; rep < REP; ++rep) {
        s1aA = BIG; s2aA = BIG; seaA = 0.0f; s1bA = BIG; s2bA = BIG; sebA = 0.0f;
        s1aB = BIG; s2aB = BIG; seaB = 0.0f; s1bB = BIG; s2bB = BIG; sebB = 0.0f;
#pragma unroll 2
        for (int jj = 0; jj < JTPW; ++jj) {
            const int jt = js * JTPW + jj;
            const unsigned short* base = xba + ((size_t)jt * KK * 64 + lane) * 8;
            bf16x8 aj[KK];
#pragma unroll
            for (int kk = 0; kk < KK; ++kk) aj[kk] = *(const bf16x8*)(base + kk * 64 * 8);

            f32x16 acc0 = __builtin_amdgcn_mfma_f32_32x32x16_bf16(aj[0], xi0[0], zacc, 0, 0, 0);
#pragma unroll
            for (int kk = 1; kk < KK; ++kk)
                acc0 = __builtin_amdgcn_mfma_f32_32x32x16_bf16(aj[kk], xi0[kk], acc0, 0, 0, 0);
            if (jt == it0) epi<true >(acc0, hi, il, s1aA, s2aA, seaA, s1bA, s2bA, sebA);
            else           epi<false>(acc0, hi, il, s1aA, s2aA, seaA, s1bA, s2bA, sebA);

            f32x16 acc1 = __builtin_amdgcn_mfma_f32_32x32x16_bf16(aj[0], xi1[0], zacc, 0, 0, 0);
#pragma unroll
            for (int kk = 1; kk < KK; ++kk)
                acc1 = __builtin_amdgcn_mfma_f32_32x32x16_bf16(aj[kk], xi1[kk], acc1, 0, 0, 0);
            if (jt == it1) epi<true >(acc1, hi, il, s1aB, s2aB, seaB, s1bB, s2bB, sebB);
            else           epi<false>(acc1, hi, il, s1aB, s2aB, seaB, s1bB, s2bB, sebB);
        }
        if (rep != REP - 1) {   // keep this rep's results live (anti-DCE), then reset
            asm volatile("" : "+v"(s1aA), "+v"(s2aA), "+v"(seaA), "+v"(s1bA), "+v"(s2bA), "+v"(sebA));
            asm volatile("" : "+v"(s1aB), "+v"(s2aB), "+v"(seaB), "+v"(s1bB), "+v"(s2bB), "+v"(sebB));
        }
    }

    // itile 0: merge even/odd, then lane <-> lane^32 (same i, disjoint j rows)
    {
        float s1 = fminf(s1aA, s1bA);
        float s2 = fminf(fmaxf(s1aA, s1bA), fminf(s2aA, s2bA));
        float se = seaA + sebA;
        const float o1 = __shfl_xor(s1, 32);
        const float o2 = __shfl_xor(s2, 32);
        const float os = __shfl_xor(se, 32);
        const float n1 = fminf(s1, o1);
        const float n2 = fminf(fmaxf(s1, o1), fminf(s2, o2));
        s1 = n1; s2 = n2; se += os;
        if (lane < 32) {
            float* P = partials + (size_t)(it0 * JSPLIT + js) * 96;
            P[lane] = s1; P[32 + lane] = s2; P[64 + lane] = se;
        }
    }
    // itile 1
    {
        float s1 = fminf(s1aB, s1bB);
        float s2 = fminf(fmaxf(s1aB, s1bB), fminf(s2aB, s2bB));
        float se = seaB + sebB;
        const float o1 = __shfl_xor(s1, 32);
        const float o2 = __shfl_xor(s2, 32);
        const float os = __shfl_xor(se, 32);
        const float n1 = fminf(s1, o1);
        const float n2 = fminf(fmaxf(s1, o1), fminf(s2, o2));
        s1 = n1; s2 = n2; se += os;
        if (lane < 32) {
            float* P = partials + (size_t)(it1 * JSPLIT + js) * 96;
            P[lane] = s1; P[32 + lane] = s2; P[64 + lane] = se;
        }
    }
}

__global__ __launch_bounds__(1024) void merge_kernel(const float* __restrict__ partials,
                                                     float* __restrict__ bsum) {
    __shared__ float s_s[16];
    const int t = threadIdx.x;
    const int p = blockIdx.x * 1024 + t;      // point index
    const int itile = p >> 5, il = p & 31;
    const float* P = partials + (size_t)itile * JSPLIT * 96;
    float a1 = P[il], a2 = P[32 + il], as = P[64 + il];
#pragma unroll
    for (int jsp = 1; jsp < JSPLIT; ++jsp) {
        const float* Q = P + jsp * 96;
        const float b1 = Q[il], b2 = Q[32 + il];
        const float m1 = fminf(a1, b1);
        const float m2 = fminf(fmaxf(a1, b1), fminf(a2, b2));
        a1 = m1; a2 = m2; as += Q[64 + il];
    }
    float sum = 0.5f * LN2 * (sqrtf(a1) + sqrtf(a2)) + logf(EXPBIAS * as);
#pragma unroll
    for (int off = 32; off >= 1; off >>= 1) sum += __shfl_xor(sum, off);
    if ((t & 63) == 0) s_s[t >> 6] = sum;
    __syncthreads();
    if (t == 0) {
        float tot = 0.0f;
#pragma unroll
        for (int g = 0; g < 16; ++g) tot += s_s[g];
        bsum[blockIdx.x] = tot;
    }
}

__global__ __launch_bounds__(64) void final_kernel(const float* __restrict__ bsum,
                                                   float* __restrict__ out) {
    const int t = threadIdx.x;
    float v = (t < 8) ? bsum[t] : 0.0f;
#pragma unroll
    for (int off = 4; off >= 1; off >>= 1) v += __shfl_xor(v, off);
    if (t == 0) out[0] = v * (1.0f / (float)N);
}

extern "C" void kernel_launch(void* const* d_in, const int* in_sizes, int n_in,
                              void* d_out, int out_size, void* d_ws, size_t ws_size,
                              hipStream_t stream) {
    const float* x = (const float*)d_in[0];
    float* out = (float*)d_out;
    char* ws = (char*)d_ws;
    const size_t fragN = (size_t)(N / 32) * KK * 64 * 8;   // shorts per fragment buffer
    unsigned short* xba = (unsigned short*)ws;
    unsigned short* xbb = xba + fragN;
    float* partials = (float*)(xbb + fragN);               // 256*32*96 f32 = 3.1 MB
    float* bsum = partials + (size_t)256 * JSPLIT * 96;    // 8 floats

    prep_kernel<<<(N * 8) / 256, 256, 0, stream>>>(x, xba, xbb);
    knn_mfma_kernel<<<32 * JSPLIT, 256, 0, stream>>>(xba, xbb, partials);
    merge_kernel<<<8, 1024, 0, stream>>>(partials, bsum);
    final_kernel<<<1, 64, 0, stream>>>(bsum, out);
}

// Round 9
// 112.622 us; speedup vs baseline: 1.4809x; 1.4809x over previous
//
#include <hip/hip_runtime.h>
#include <math.h>

#define N 8192
#define D 64
#define KK 5                  // K-steps of 16 (K=80: 64 data + 4 norm + 12 zero)
#define JSPLIT 64             // j-split across (jss, wave)
#define JTPW 4                // j-tiles per wave
#define LOG2E 1.4426950408889634f
#define C2 2.0813689810056077f
#define SA (-2.0f * LOG2E)
#define SB LOG2E
#define LN2 0.6931471805599453f
#define BIG 3.0e38f
#define EXPBIAS 0.9608944f
#define EXPMAGIC 1065353216.0f
#define EXPSCALE -8388608.0f

typedef short bf16x8 __attribute__((ext_vector_type(8)));
typedef float f32x16 __attribute__((ext_vector_type(16)));

static __device__ __forceinline__ unsigned short f2bf(float f) {
    unsigned int u = __float_as_uint(f);
    return (unsigned short)((u + 0x7fffu + ((u >> 16) & 1u)) >> 16);
}

// Fragment layout (validated r2-r8): 16B slot s = (tile*KK + kk)*64 + lane;
// lane l holds row (l&31), k = kk*16 + 8*(l>>5) + 0..7.
// A (xba): k<64 -> -2*log2e*x ; k=64..67 -> [nhi, nlo, 1, 1] ; rest 0
// B (xbb): k<64 ->    log2e*x ; k=64..67 -> [1, 1, nhi, nlo] ; rest 0
// => acc[j,i] = |log2e*(x_i - x_j)|^2  (norms folded into MFMA)
__global__ __launch_bounds__(256) void prep_kernel(const float* __restrict__ x,
                                                   unsigned short* __restrict__ xba,
                                                   unsigned short* __restrict__ xbb) {
    const int u = blockIdx.x * 256 + threadIdx.x;
    const int r = u >> 3, oct = u & 7;
    const float4 v0 = *(const float4*)(x + r * D + oct * 8);
    const float4 v1 = *(const float4*)(x + r * D + oct * 8 + 4);
    float s = v0.x * v0.x + v0.y * v0.y + v0.z * v0.z + v0.w * v0.w
            + v1.x * v1.x + v1.y * v1.y + v1.z * v1.z + v1.w * v1.w;
    s += __shfl_xor(s, 1); s += __shfl_xor(s, 2); s += __shfl_xor(s, 4);

    const int slot = ((r >> 5) * KK + (oct >> 1)) * 64 + (r & 31) + 32 * (oct & 1);
    uint4 wa, wb;
    wa.x = (unsigned)f2bf(SA * v0.x) | ((unsigned)f2bf(SA * v0.y) << 16);
    wa.y = (unsigned)f2bf(SA * v0.z) | ((unsigned)f2bf(SA * v0.w) << 16);
    wa.z = (unsigned)f2bf(SA * v1.x) | ((unsigned)f2bf(SA * v1.y) << 16);
    wa.w = (unsigned)f2bf(SA * v1.z) | ((unsigned)f2bf(SA * v1.w) << 16);
    wb.x = (unsigned)f2bf(SB * v0.x) | ((unsigned)f2bf(SB * v0.y) << 16);
    wb.y = (unsigned)f2bf(SB * v0.z) | ((unsigned)f2bf(SB * v0.w) << 16);
    wb.z = (unsigned)f2bf(SB * v1.x) | ((unsigned)f2bf(SB * v1.y) << 16);
    wb.w = (unsigned)f2bf(SB * v1.z) | ((unsigned)f2bf(SB * v1.w) << 16);
    *(uint4*)(xba + (size_t)slot * 8) = wa;
    *(uint4*)(xbb + (size_t)slot * 8) = wb;

    const float np = C2 * s;
    const unsigned short nhi = f2bf(np);
    const unsigned short nlo = f2bf(np - __uint_as_float((unsigned)nhi << 16));
    const int nbase = ((r >> 5) * KK + 4) * 64 + (r & 31);
    const unsigned ONE2 = 0x3f803f80u;
    if (oct == 0) {
        uint4 w; w.x = (unsigned)nhi | ((unsigned)nlo << 16); w.y = ONE2; w.z = 0; w.w = 0;
        *(uint4*)(xba + (size_t)nbase * 8) = w;
    } else if (oct == 1) {
        uint4 w; w.x = 0; w.y = 0; w.z = 0; w.w = 0;
        *(uint4*)(xba + (size_t)(nbase + 32) * 8) = w;
    } else if (oct == 2) {
        uint4 w; w.x = ONE2; w.y = (unsigned)nhi | ((unsigned)nlo << 16); w.z = 0; w.w = 0;
        *(uint4*)(xbb + (size_t)nbase * 8) = w;
    } else if (oct == 3) {
        uint4 w; w.x = 0; w.y = 0; w.z = 0; w.w = 0;
        *(uint4*)(xbb + (size_t)(nbase + 32) * 8) = w;
    }
}

template<bool DIAG>
static __device__ __forceinline__ void epi(const f32x16& acc, int hi, int il,
                                           float& s1a, float& s2a, float& sea,
                                           float& s1b, float& s2b, float& seb) {
#pragma unroll
    for (int q = 0; q < 16; ++q) {
        float sq = acc[q];
        if (DIAG) {
            sq = fmaxf(sq, 0.0f);
            const bool self = ((q & 3) + 8 * (q >> 2) + 4 * hi) == il;
            sq = self ? BIG : sq;      // self: bit-exp saturates to -0.0, harmless
        }
        const float dd = __builtin_amdgcn_sqrtf(sq);       // log2e * dist
        const float ef = fmaf(dd, EXPSCALE, EXPMAGIC);     // fast 2^(-dd)
        const float e  = __int_as_float((int)ef);
        if (q & 1) { seb += e; s2b = __builtin_amdgcn_fmed3f(s1b, s2b, sq); s1b = fminf(s1b, sq); }
        else       { sea += e; s2a = __builtin_amdgcn_fmed3f(s1a, s2a, sq); s1a = fminf(s1a, sq); }
    }
}

__global__ __launch_bounds__(256, 8) void knn_mfma_kernel(
        const unsigned short* __restrict__ xba,
        const unsigned short* __restrict__ xbb,
        float* __restrict__ partials) {
    __shared__ float s_red[8 * 96];           // 4 waves x 2 itiles

    const int t = threadIdx.x;
    const int lane = t & 63;
    const int w = t >> 6;
    const int ipp = blockIdx.x >> 4;          // 0..127 : itile pair
    const int jss = blockIdx.x & 15;          // 16 j-slices; wave refines to js = jss*4+w
    const int it0 = ipp * 2, it1 = it0 + 1;
    const int il = lane & 31, hi = lane >> 5;

    bf16x8 xi0[KK], xi1[KK];
#pragma unroll
    for (int kk = 0; kk < KK; ++kk) {
        xi0[kk] = *(const bf16x8*)(xbb + ((size_t)(it0 * KK + kk) * 64 + lane) * 8);
        xi1[kk] = *(const bf16x8*)(xbb + ((size_t)(it1 * KK + kk) * 64 + lane) * 8);
    }

    float s1aA = BIG, s2aA = BIG, seaA = 0.0f, s1bA = BIG, s2bA = BIG, sebA = 0.0f;
    float s1aB = BIG, s2aB = BIG, seaB = 0.0f, s1bB = BIG, s2bB = BIG, sebB = 0.0f;
    const f32x16 zacc = {};

    const int jt0 = (jss * 4 + w) * JTPW;
#pragma unroll 2
    for (int jj = 0; jj < JTPW; ++jj) {
        const int jt = jt0 + jj;
        const unsigned short* base = xba + ((size_t)jt * KK * 64 + lane) * 8;
        bf16x8 aj[KK];
#pragma unroll
        for (int kk = 0; kk < KK; ++kk) aj[kk] = *(const bf16x8*)(base + kk * 64 * 8);

        f32x16 acc0 = __builtin_amdgcn_mfma_f32_32x32x16_bf16(aj[0], xi0[0], zacc, 0, 0, 0);
#pragma unroll
        for (int kk = 1; kk < KK; ++kk)
            acc0 = __builtin_amdgcn_mfma_f32_32x32x16_bf16(aj[kk], xi0[kk], acc0, 0, 0, 0);
        if (jt == it0) epi<true >(acc0, hi, il, s1aA, s2aA, seaA, s1bA, s2bA, sebA);
        else           epi<false>(acc0, hi, il, s1aA, s2aA, seaA, s1bA, s2bA, sebA);

        f32x16 acc1 = __builtin_amdgcn_mfma_f32_32x32x16_bf16(aj[0], xi1[0], zacc, 0, 0, 0);
#pragma unroll
        for (int kk = 1; kk < KK; ++kk)
            acc1 = __builtin_amdgcn_mfma_f32_32x32x16_bf16(aj[kk], xi1[kk], acc1, 0, 0, 0);
        if (jt == it1) epi<true >(acc1, hi, il, s1aB, s2aB, seaB, s1bB, s2bB, sebB);
        else           epi<false>(acc1, hi, il, s1aB, s2aB, seaB, s1bB, s2bB, sebB);
    }

    // per-itile: merge even/odd chains, then lane <-> lane^32 (disjoint j rows)
    {
        float s1 = fminf(s1aA, s1bA);
        float s2 = fminf(fmaxf(s1aA, s1bA), fminf(s2aA, s2bA));
        float se = seaA + sebA;
        const float o1 = __shfl_xor(s1, 32), o2 = __shfl_xor(s2, 32), os = __shfl_xor(se, 32);
        const float n1 = fminf(s1, o1);
        const float n2 = fminf(fmaxf(s1, o1), fminf(s2, o2));
        if (lane < 32) {
            float* R = s_red + (w * 2 + 0) * 96;
            R[lane] = n1; R[32 + lane] = n2; R[64 + lane] = se + os;
        }
    }
    {
        float s1 = fminf(s1aB, s1bB);
        float s2 = fminf(fmaxf(s1aB, s1bB), fminf(s2aB, s2bB));
        float se = seaB + sebB;
        const float o1 = __shfl_xor(s1, 32), o2 = __shfl_xor(s2, 32), os = __shfl_xor(se, 32);
        const float n1 = fminf(s1, o1);
        const float n2 = fminf(fmaxf(s1, o1), fminf(s2, o2));
        if (lane < 32) {
            float* R = s_red + (w * 2 + 1) * 96;
            R[lane] = n1; R[32 + lane] = n2; R[64 + lane] = se + os;
        }
    }
    __syncthreads();
    if (t < 64) {   // merge 4 waves per itile; t<32 -> it0, t>=32 -> it1
        const int sel = t >> 5, i2 = t & 31;
        float a1 = s_red[sel * 96 + i2], a2 = s_red[sel * 96 + 32 + i2], as = s_red[sel * 96 + 64 + i2];
#pragma unroll
        for (int g = 1; g < 4; ++g) {
            const float* R = s_red + (g * 2 + sel) * 96;
            const float b1 = R[i2], b2 = R[32 + i2];
            const float m1 = fminf(a1, b1);
            const float m2 = fminf(fmaxf(a1, b1), fminf(a2, b2));
            a1 = m1; a2 = m2; as += R[64 + i2];
        }
        float* P = partials + (size_t)((it0 + sel) * 16 + jss) * 96;
        P[i2] = a1; P[32 + i2] = a2; P[64 + i2] = as;
    }
}

__global__ __launch_bounds__(256) void merge_kernel(const float* __restrict__ partials,
                                                    float* __restrict__ bsum) {
    __shared__ float s_s[4];
    const int t = threadIdx.x;
    const int p = blockIdx.x * 256 + t;       // point index
    const int itile = p >> 5, il = p & 31;
    const float* P = partials + (size_t)itile * 16 * 96;
    float a1 = P[il], a2 = P[32 + il], as = P[64 + il];
#pragma unroll
    for (int jss = 1; jss < 16; ++jss) {
        const float* Q = P + jss * 96;
        const float b1 = Q[il], b2 = Q[32 + il];
        const float m1 = fminf(a1, b1);
        const float m2 = fminf(fmaxf(a1, b1), fminf(a2, b2));
        a1 = m1; a2 = m2; as += Q[64 + il];
    }
    float sum = 0.5f * LN2 * (sqrtf(a1) + sqrtf(a2)) + logf(EXPBIAS * as);
#pragma unroll
    for (int off = 32; off >= 1; off >>= 1) sum += __shfl_xor(sum, off);
    if ((t & 63) == 0) s_s[t >> 6] = sum;
    __syncthreads();
    if (t == 0) bsum[blockIdx.x] = s_s[0] + s_s[1] + s_s[2] + s_s[3];
}

__global__ __launch_bounds__(64) void final_kernel(const float* __restrict__ bsum,
                                                   float* __restrict__ out) {
    const int t = threadIdx.x;
    float v = (t < 32) ? bsum[t] : 0.0f;
#pragma unroll
    for (int off = 16; off >= 1; off >>= 1) v += __shfl_xor(v, off);
    if (t == 0) out[0] = v * (1.0f / (float)N);
}

extern "C" void kernel_launch(void* const* d_in, const int* in_sizes, int n_in,
                              void* d_out, int out_size, void* d_ws, size_t ws_size,
                              hipStream_t stream) {
    const float* x = (const float*)d_in[0];
    float* out = (float*)d_out;
    char* ws = (char*)d_ws;
    const size_t fragN = (size_t)(N / 32) * KK * 64 * 8;   // shorts per fragment buffer
    unsigned short* xba = (unsigned short*)ws;
    unsigned short* xbb = xba + fragN;
    float* partials = (float*)(xbb + fragN);               // 256*16*96 f32 = 1.57 MB
    float* bsum = partials + (size_t)256 * 16 * 96;        // 32 floats

    prep_kernel<<<(N * 8) / 256, 256, 0, stream>>>(x, xba, xbb);
    knn_mfma_kernel<<<128 * 16, 256, 0, stream>>>(xba, xbb, partials);
    merge_kernel<<<32, 256, 0, stream>>>(partials, bsum);
    final_kernel<<<1, 64, 0, stream>>>(bsum, out);
}

// Round 10
// 35.655 us; speedup vs baseline: 4.6776x; 3.1587x over previous
//
#include <hip/hip_runtime.h>
#include <math.h>

#define N 8192
#define D 64
#define KK 5                  // K-steps of 16 (K=80: 64 data + 4 norm + 12 zero)
#define JTPW 4                // j-tiles per wave
#define LOG2E 1.4426950408889634f
#define C2 2.0813689810056077f
#define SA (-2.0f * LOG2E)
#define SB LOG2E
#define LN2 0.6931471805599453f
#define BIG 3.0e38f
#define EXPBIAS 0.9608944f
#define EXPMAGIC 1065353216.0f
#define EXPSCALE -8388608.0f

typedef short bf16x8 __attribute__((ext_vector_type(8)));
typedef float f32x16 __attribute__((ext_vector_type(16)));

static __device__ __forceinline__ unsigned short f2bf(float f) {
    unsigned int u = __float_as_uint(f);
    return (unsigned short)((u + 0x7fffu + ((u >> 16) & 1u)) >> 16);
}

// Fragment layout (validated r2-r9): 16B slot s = (tile*KK + kk)*64 + lane;
// lane l holds row (l&31), k = kk*16 + 8*(l>>5) + 0..7.
// A (xba): k<64 -> -2*log2e*x ; k=64..67 -> [nhi, nlo, 1, 1] ; rest 0
// B (xbb): k<64 ->    log2e*x ; k=64..67 -> [1, 1, nhi, nlo] ; rest 0
// => acc[j,i] = |log2e*(x_i - x_j)|^2  (norms folded into MFMA)
__global__ __launch_bounds__(256) void prep_kernel(const float* __restrict__ x,
                                                   unsigned short* __restrict__ xba,
                                                   unsigned short* __restrict__ xbb) {
    const int u = blockIdx.x * 256 + threadIdx.x;
    const int r = u >> 3, oct = u & 7;
    const float4 v0 = *(const float4*)(x + r * D + oct * 8);
    const float4 v1 = *(const float4*)(x + r * D + oct * 8 + 4);
    float s = v0.x * v0.x + v0.y * v0.y + v0.z * v0.z + v0.w * v0.w
            + v1.x * v1.x + v1.y * v1.y + v1.z * v1.z + v1.w * v1.w;
    s += __shfl_xor(s, 1); s += __shfl_xor(s, 2); s += __shfl_xor(s, 4);

    const int slot = ((r >> 5) * KK + (oct >> 1)) * 64 + (r & 31) + 32 * (oct & 1);
    uint4 wa, wb;
    wa.x = (unsigned)f2bf(SA * v0.x) | ((unsigned)f2bf(SA * v0.y) << 16);
    wa.y = (unsigned)f2bf(SA * v0.z) | ((unsigned)f2bf(SA * v0.w) << 16);
    wa.z = (unsigned)f2bf(SA * v1.x) | ((unsigned)f2bf(SA * v1.y) << 16);
    wa.w = (unsigned)f2bf(SA * v1.z) | ((unsigned)f2bf(SA * v1.w) << 16);
    wb.x = (unsigned)f2bf(SB * v0.x) | ((unsigned)f2bf(SB * v0.y) << 16);
    wb.y = (unsigned)f2bf(SB * v0.z) | ((unsigned)f2bf(SB * v0.w) << 16);
    wb.z = (unsigned)f2bf(SB * v1.x) | ((unsigned)f2bf(SB * v1.y) << 16);
    wb.w = (unsigned)f2bf(SB * v1.z) | ((unsigned)f2bf(SB * v1.w) << 16);
    *(uint4*)(xba + (size_t)slot * 8) = wa;
    *(uint4*)(xbb + (size_t)slot * 8) = wb;

    const float np = C2 * s;
    const unsigned short nhi = f2bf(np);
    const unsigned short nlo = f2bf(np - __uint_as_float((unsigned)nhi << 16));
    const int nbase = ((r >> 5) * KK + 4) * 64 + (r & 31);
    const unsigned ONE2 = 0x3f803f80u;
    if (oct == 0) {
        uint4 w; w.x = (unsigned)nhi | ((unsigned)nlo << 16); w.y = ONE2; w.z = 0; w.w = 0;
        *(uint4*)(xba + (size_t)nbase * 8) = w;
    } else if (oct == 1) {
        uint4 w; w.x = 0; w.y = 0; w.z = 0; w.w = 0;
        *(uint4*)(xba + (size_t)(nbase + 32) * 8) = w;
    } else if (oct == 2) {
        uint4 w; w.x = ONE2; w.y = (unsigned)nhi | ((unsigned)nlo << 16); w.z = 0; w.w = 0;
        *(uint4*)(xbb + (size_t)nbase * 8) = w;
    } else if (oct == 3) {
        uint4 w; w.x = 0; w.y = 0; w.z = 0; w.w = 0;
        *(uint4*)(xbb + (size_t)(nbase + 32) * 8) = w;
    }
}

template<bool DIAG>
static __device__ __forceinline__ void epi(const f32x16& acc, int hi, int il,
                                           float& s1a, float& s2a, float& sea,
                                           float& s1b, float& s2b, float& seb) {
#pragma unroll
    for (int q = 0; q < 16; ++q) {
        float sq = acc[q];
        if (DIAG) {
            sq = fmaxf(sq, 0.0f);
            const bool self = ((q & 3) + 8 * (q >> 2) + 4 * hi) == il;
            sq = self ? BIG : sq;      // self: bit-exp saturates to -0.0, harmless
        }
        const float dd = __builtin_amdgcn_sqrtf(sq);       // log2e * dist
        const float ef = fmaf(dd, EXPSCALE, EXPMAGIC);     // fast 2^(-dd)
        const float e  = __int_as_float((int)ef);
        if (q & 1) { seb += e; s2b = __builtin_amdgcn_fmed3f(s1b, s2b, sq); s1b = fminf(s1b, sq); }
        else       { sea += e; s2a = __builtin_amdgcn_fmed3f(s1a, s2a, sq); s1a = fminf(s1a, sq); }
    }
}

__global__ __launch_bounds__(256, 4) void knn_mfma_kernel(
        const unsigned short* __restrict__ xba,
        const unsigned short* __restrict__ xbb,
        float* __restrict__ partials) {
    __shared__ float s_red[8 * 96];           // 4 waves x 2 itiles

    const int t = threadIdx.x;
    const int lane = t & 63;
    const int w = t >> 6;
    const int ipp = blockIdx.x >> 4;          // 0..127 : itile pair
    const int jss = blockIdx.x & 15;          // 16 j-slices; wave refines to js = jss*4+w
    const int it0 = ipp * 2, it1 = it0 + 1;
    const int il = lane & 31, hi = lane >> 5;

    bf16x8 xi0[KK], xi1[KK];
#pragma unroll
    for (int kk = 0; kk < KK; ++kk) {
        xi0[kk] = *(const bf16x8*)(xbb + ((size_t)(it0 * KK + kk) * 64 + lane) * 8);
        xi1[kk] = *(const bf16x8*)(xbb + ((size_t)(it1 * KK + kk) * 64 + lane) * 8);
    }

    float s1aA = BIG, s2aA = BIG, seaA = 0.0f, s1bA = BIG, s2bA = BIG, sebA = 0.0f;
    float s1aB = BIG, s2aB = BIG, seaB = 0.0f, s1bB = BIG, s2bB = BIG, sebB = 0.0f;
    const f32x16 zacc = {};

    const int jt0 = (jss * 4 + w) * JTPW;
#pragma unroll 2
    for (int jj = 0; jj < JTPW; ++jj) {
        const int jt = jt0 + jj;
        const unsigned short* base = xba + ((size_t)jt * KK * 64 + lane) * 8;
        bf16x8 aj[KK];
#pragma unroll
        for (int kk = 0; kk < KK; ++kk) aj[kk] = *(const bf16x8*)(base + kk * 64 * 8);

        f32x16 acc0 = __builtin_amdgcn_mfma_f32_32x32x16_bf16(aj[0], xi0[0], zacc, 0, 0, 0);
#pragma unroll
        for (int kk = 1; kk < KK; ++kk)
            acc0 = __builtin_amdgcn_mfma_f32_32x32x16_bf16(aj[kk], xi0[kk], acc0, 0, 0, 0);
        if (jt == it0) epi<true >(acc0, hi, il, s1aA, s2aA, seaA, s1bA, s2bA, sebA);
        else           epi<false>(acc0, hi, il, s1aA, s2aA, seaA, s1bA, s2bA, sebA);

        f32x16 acc1 = __builtin_amdgcn_mfma_f32_32x32x16_bf16(aj[0], xi1[0], zacc, 0, 0, 0);
#pragma unroll
        for (int kk = 1; kk < KK; ++kk)
            acc1 = __builtin_amdgcn_mfma_f32_32x32x16_bf16(aj[kk], xi1[kk], acc1, 0, 0, 0);
        if (jt == it1) epi<true >(acc1, hi, il, s1aB, s2aB, seaB, s1bB, s2bB, sebB);
        else           epi<false>(acc1, hi, il, s1aB, s2aB, seaB, s1bB, s2bB, sebB);
    }

    // per-itile: merge even/odd chains, then lane <-> lane^32 (disjoint j rows)
    {
        float s1 = fminf(s1aA, s1bA);
        float s2 = fminf(fmaxf(s1aA, s1bA), fminf(s2aA, s2bA));
        float se = seaA + sebA;
        const float o1 = __shfl_xor(s1, 32), o2 = __shfl_xor(s2, 32), os = __shfl_xor(se, 32);
        const float n1 = fminf(s1, o1);
        const float n2 = fminf(fmaxf(s1, o1), fminf(s2, o2));
        if (lane < 32) {
            float* R = s_red + (w * 2 + 0) * 96;
            R[lane] = n1; R[32 + lane] = n2; R[64 + lane] = se + os;
        }
    }
    {
        float s1 = fminf(s1aB, s1bB);
        float s2 = fminf(fmaxf(s1aB, s1bB), fminf(s2aB, s2bB));
        float se = seaB + sebB;
        const float o1 = __shfl_xor(s1, 32), o2 = __shfl_xor(s2, 32), os = __shfl_xor(se, 32);
        const float n1 = fminf(s1, o1);
        const float n2 = fminf(fmaxf(s1, o1), fminf(s2, o2));
        if (lane < 32) {
            float* R = s_red + (w * 2 + 1) * 96;
            R[lane] = n1; R[32 + lane] = n2; R[64 + lane] = se + os;
        }
    }
    __syncthreads();
    if (t < 64) {   // merge 4 waves per itile; t<32 -> it0, t>=32 -> it1
        const int sel = t >> 5, i2 = t & 31;
        float a1 = s_red[sel * 96 + i2], a2 = s_red[sel * 96 + 32 + i2], as = s_red[sel * 96 + 64 + i2];
#pragma unroll
        for (int g = 1; g < 4; ++g) {
            const float* R = s_red + (g * 2 + sel) * 96;
            const float b1 = R[i2], b2 = R[32 + i2];
            const float m1 = fminf(a1, b1);
            const float m2 = fminf(fmaxf(a1, b1), fminf(a2, b2));
            a1 = m1; a2 = m2; as += R[64 + i2];
        }
        float* P = partials + (size_t)((it0 + sel) * 16 + jss) * 96;
        P[i2] = a1; P[32 + i2] = a2; P[64 + i2] = as;
    }
}

__global__ __launch_bounds__(256) void merge_kernel(const float* __restrict__ partials,
                                                    float* __restrict__ bsum) {
    __shared__ float s_s[4];
    const int t = threadIdx.x;
    const int p = blockIdx.x * 256 + t;       // point index
    const int itile = p >> 5, il = p & 31;
    const float* P = partials + (size_t)itile * 16 * 96;
    float a1 = P[il], a2 = P[32 + il], as = P[64 + il];
#pragma unroll
    for (int jss = 1; jss < 16; ++jss) {
        const float* Q = P + jss * 96;
        const float b1 = Q[il], b2 = Q[32 + il];
        const float m1 = fminf(a1, b1);
        const float m2 = fminf(fmaxf(a1, b1), fminf(a2, b2));
        a1 = m1; a2 = m2; as += Q[64 + il];
    }
    float sum = 0.5f * LN2 * (sqrtf(a1) + sqrtf(a2)) + logf(EXPBIAS * as);
#pragma unroll
    for (int off = 32; off >= 1; off >>= 1) sum += __shfl_xor(sum, off);
    if ((t & 63) == 0) s_s[t >> 6] = sum;
    __syncthreads();
    if (t == 0) bsum[blockIdx.x] = s_s[0] + s_s[1] + s_s[2] + s_s[3];
}

__global__ __launch_bounds__(64) void final_kernel(const float* __restrict__ bsum,
                                                   float* __restrict__ out) {
    const int t = threadIdx.x;
    float v = (t < 32) ? bsum[t] : 0.0f;
#pragma unroll
    for (int off = 16; off >= 1; off >>= 1) v += __shfl_xor(v, off);
    if (t == 0) out[0] = v * (1.0f / (float)N);
}

extern "C" void kernel_launch(void* const* d_in, const int* in_sizes, int n_in,
                              void* d_out, int out_size, void* d_ws, size_t ws_size,
                              hipStream_t stream) {
    const float* x = (const float*)d_in[0];
    float* out = (float*)d_out;
    char* ws = (char*)d_ws;
    const size_t fragN = (size_t)(N / 32) * KK * 64 * 8;   // shorts per fragment buffer
    unsigned short* xba = (unsigned short*)ws;
    unsigned short* xbb = xba + fragN;
    float* partials = (float*)(xbb + fragN);               // 256*16*96 f32 = 1.57 MB
    float* bsum = partials + (size_t)256 * 16 * 96;        // 32 floats

    prep_kernel<<<(N * 8) / 256, 256, 0, stream>>>(x, xba, xbb);
    knn_mfma_kernel<<<128 * 16, 256, 0, stream>>>(xba, xbb, partials);
    merge_kernel<<<32, 256, 0, stream>>>(partials, bsum);
    final_kernel<<<1, 64, 0, stream>>>(bsum, out);
}